// Round 13
// baseline (95.069 us; speedup 1.0000x reference)
//
#include <hip/hip_runtime.h>

#define B_ 4
#define C_ 256
#define N_ 4096
#define INTER_ 32

typedef __attribute__((ext_vector_type(8))) short short8;
typedef __attribute__((ext_vector_type(4))) float f32x4;
typedef __attribute__((ext_vector_type(16))) float f32x16;
typedef __attribute__((ext_vector_type(4))) unsigned int u32x4;

// LDS map (bytes): V[jq][3 slots][16384] | K[jq][2][2048] | P[jq][2][rg][2048]
//                  | F[jq][2][rg][160] | m/l[4][32]
#define VOFF  0
#define KOFF  98304
#define POFF  106496
#define FOFF  122880
#define MOFF  124160
#define LDSSZ 125184

static __device__ __forceinline__ unsigned short f2bf(float f) {
    unsigned int u = __builtin_bit_cast(unsigned int, f);
    u += 0x7fff + ((u >> 16) & 1);   // round-to-nearest-even
    return (unsigned short)(u >> 16);
}

static __device__ __forceinline__ unsigned int cvtpk(float lo, float hi) {
    unsigned int r;
    asm("v_cvt_pk_bf16_f32 %0, %1, %2" : "=v"(r) : "v"(lo), "v"(hi));
    return r;
}

static __device__ __forceinline__ void pl32swap(unsigned int& a, unsigned int& b) {
    asm("v_permlane32_swap_b32 %0, %1" : "+v"(a), "+v"(b));
}

static __device__ __forceinline__ float exp2a(float x) {   // bare v_exp_f32: 2^x
    float r;
    asm("v_exp_f32 %0, %1" : "=v"(r) : "v"(x));
    return r;
}

static __device__ __forceinline__ void gload16(const void* g, void* l) {
    __builtin_amdgcn_global_load_lds(
        (const __attribute__((address_space(1))) void*)g,
        (__attribute__((address_space(3))) void*)l, 16, 0, 0);
}

// ---------------- W prep: concat + bf16 convert ----------------
__global__ __launch_bounds__(256) void prep_kernel(
    const float* __restrict__ Wq, const float* __restrict__ Wk,
    const float* __restrict__ Wv, unsigned short* __restrict__ wb)
{
    int i = blockIdx.x * 256 + threadIdx.x;      // 0 .. 320*256-1
    int row = i >> 8, col = i & 255;
    float v;
    if (row < 32)      v = Wq[row * 256 + col];
    else if (row < 64) v = Wk[(row - 32) * 256 + col];
    else               v = Wv[(row - 64) * 256 + col];
    wb[i] = f2bf(v);
}

// ---------------- QKV projection as MFMA GEMM (unchanged from r10) ---------
__global__ __launch_bounds__(256) void qkv_kernel(
    const float* __restrict__ x, const unsigned short* __restrict__ wb,
    const float* __restrict__ bq, const float* __restrict__ bk,
    const float* __restrict__ bv,
    unsigned short* __restrict__ qb, unsigned short* __restrict__ kfrag,
    unsigned short* __restrict__ vfrag)
{
    const int tid  = threadIdx.x;
    const int wave = tid >> 6;
    const int lane = tid & 63;
    const int l31  = lane & 31;
    const int h2   = lane >> 5;
    const int b    = blockIdx.x >> 6;
    const int n0   = (blockIdx.x & 63) * 64;

    __shared__ unsigned int xsh[64 * 129];   // [n][c/2] u32, row stride 129 dwords

    {
        const float* xb = x + ((size_t)b * C_ + 64 * wave) * N_ + n0 + lane;
        unsigned int* dst = xsh + (size_t)lane * 129 + 32 * wave;
        #pragma unroll 8
        for (int s = 0; s < 32; ++s) {
            float v0 = xb[(size_t)(2 * s) * N_];
            float v1 = xb[(size_t)(2 * s + 1) * N_];
            dst[s] = (unsigned int)f2bf(v0) | ((unsigned int)f2bf(v1) << 16);
        }
    }
    __syncthreads();

    const float rs = 0.25504183f;   // log2(e)/sqrt(32) folded into q

    #pragma unroll
    for (int u = 0; u < 5; ++u) {
        const int unit = wave + 4 * u;       // 0..19
        const int ch = unit >> 1;            // 0..9
        const int ns = unit & 1;
        const int ncol = n0 + 32 * ns + l31;
        const int jt = (n0 >> 5) + ns;

        const float* bias = (ch == 0) ? bq : (ch == 1) ? bk : (bv + (ch - 2) * 32);
        f32x16 acc;
        #pragma unroll
        for (int r = 0; r < 16; ++r)
            acc[r] = bias[(r & 3) + 8 * (r >> 2) + 4 * h2];

        const unsigned short* wrow = wb + ((size_t)(ch * 32 + l31)) * 256 + 8 * h2;
        const unsigned int*   xrow = xsh + (size_t)(32 * ns + l31) * 129 + 4 * h2;

        #pragma unroll
        for (int kk = 0; kk < 16; ++kk) {
            short8 wa = *reinterpret_cast<const short8*>(wrow + 16 * kk);
            short8 xf = *reinterpret_cast<const short8*>(xrow + 8 * kk);
            acc = __builtin_amdgcn_mfma_f32_32x32x16_bf16(wa, xf, acc, 0, 0, 0);
        }

        if (ch == 0) {
            unsigned short* dst = qb + ((size_t)b * N_ + ncol) * 32;
            #pragma unroll
            for (int q = 0; q < 4; ++q) {
                unsigned int w0 = (unsigned int)f2bf(acc[4 * q] * rs)
                                | ((unsigned int)f2bf(acc[4 * q + 1] * rs) << 16);
                unsigned int w1 = (unsigned int)f2bf(acc[4 * q + 2] * rs)
                                | ((unsigned int)f2bf(acc[4 * q + 3] * rs) << 16);
                unsigned int* p = reinterpret_cast<unsigned int*>(dst + 4 * h2 + 8 * q);
                p[0] = w0; p[1] = w1;
            }
        } else if (ch == 1) {
            unsigned short* kt = kfrag + ((size_t)b * 128 + jt) * 1024;
            #pragma unroll
            for (int r = 0; r < 16; ++r) {
                const int co = (r & 3) + 8 * (r >> 2) + 4 * h2;
                const int addr = ((co >> 4) << 9) + ((l31 + 32 * ((co >> 3) & 1)) << 3)
                               + (co & 7);
                kt[addr] = f2bf(acc[r]);
            }
        } else {
            const int g = ch - 2;
            unsigned short* vt_ = vfrag + (((size_t)b * 128 + jt) * 8 + g) * 1024;
            #pragma unroll
            for (int r = 0; r < 16; ++r) {
                const int co = (r & 3) + 8 * (r >> 2) + 4 * h2;
                const int addr = ((l31 >> 4) << 9) + ((co + 32 * ((l31 >> 3) & 1)) << 3)
                               + (l31 & 7);
                vt_[addr] = f2bf(acc[r]);
            }
        }
    }
}

// ---------------- Flash attention: producer/consumer wave specialization ----
// Flat grid 256 (XCD-batch affinity), block 512 = 8 waves:
//   waves 0-3 PRODUCERS (jq = w&1, rg = w>>1): QK^T + softmax for 32 q-rows,
//     emit P B-fragments + defer-max corr/flag to LDS; stage next K chunk.
//   waves 4-7 CONSUMERS (jq = w&1, ch = (w-4)>>1): pure PV, 16 MFMA/step over
//     both row-groups x 4 channel-groups; stage next V half-tile.
// Wave w -> SIMD w%4 co-locates one producer + one consumer per SIMD, so
// softmax VALU and PV MFMA grind CONCURRENTLY. Consumer runs one tile behind
// (reads P[t-1], V[t-1]); V triple-buffered, K/P double-buffered; single
// __syncthreads per step carries all cross-role handoffs.
__global__ __launch_bounds__(512, 2) void attn_kernel(
    const unsigned short* __restrict__ qb, const unsigned short* __restrict__ kfrag,
    const unsigned short* __restrict__ vfrag,
    const float* __restrict__ x, const float* __restrict__ gamma,
    float* __restrict__ out)
{
    const int tid  = threadIdx.x;
    const int wave = tid >> 6;
    const int lane = tid & 63;
    const int l31  = lane & 31;
    const int h2   = lane >> 5;
    const bool prod = wave < 4;
    const int jq = wave & 1;                 // same formula both roles
    const int rg = wave >> 1;                // producers: 0/1 (rows)
    const int ch = (wave - 4) >> 1;          // consumers: 0/1 (channels)

    // XCD-affinity decode (bijective): bid = slot*8 + xcd
    const int bid  = blockIdx.x;
    const int xcd  = bid & 7;
    const int slot = bid >> 3;
    const int b    = xcd >> 1;               // 2 XCDs per batch
    const int ib   = slot * 2 + (xcd & 1);   // i-tile 0..63
    const int i0   = ib * 64;

    __shared__ char lds[LDSSZ];

    const unsigned short* vtb = vfrag + (size_t)b * 128 * 8192;
    const unsigned short* ktb = kfrag + (size_t)b * 128 * 1024;

    char* ldsV = lds + VOFF + jq * 49152;    // 3 slots x 16384
    char* ldsK = lds + KOFF + jq * 4096;     // 2 bufs x 2048
    const int jt0 = jq * 64;                 // this jq-half's tile base

    // producer state
    short8 qf0{}, qf1{};
    float m_run = 0.f, l_run = 0.f;          // defer-max init (exp2 domain)
    if (prod) {
        const unsigned short* qbase =
            qb + ((size_t)b * N_ + i0 + rg * 32 + l31) * 32 + 8 * h2;
        qf0 = *reinterpret_cast<const short8*>(qbase);
        qf1 = *reinterpret_cast<const short8*>(qbase + 16);
    }
    // consumer state
    f32x16 acc[2][4];
    #pragma unroll
    for (int a = 0; a < 2; ++a)
        #pragma unroll
        for (int g = 0; g < 4; ++g)
            #pragma unroll
            for (int r = 0; r < 16; ++r) acc[a][g][r] = 0.f;

    const f32x16 z16 = {};

    // ---- producer step: QK^T + softmax for tile T -> P/F[buf = T&1] ----
#define PROD_STEP(T) do {                                                     \
        const int kb_ = (T) & 1;                                              \
        const char* kc = ldsK + kb_ * 2048;                                   \
        short8 ka0 = *reinterpret_cast<const short8*>(kc + lane * 16);        \
        short8 ka1 = *reinterpret_cast<const short8*>(kc + 1024 + lane * 16); \
        f32x16 s = __builtin_amdgcn_mfma_f32_32x32x16_bf16(ka0, qf0, z16, 0, 0, 0); \
        s = __builtin_amdgcn_mfma_f32_32x32x16_bf16(ka1, qf1, s, 0, 0, 0);    \
        float a0 = fmaxf(s[0], s[8]),  a1 = fmaxf(s[1], s[9]);                \
        float a2 = fmaxf(s[2], s[10]), a3 = fmaxf(s[3], s[11]);               \
        float a4 = fmaxf(s[4], s[12]), a5 = fmaxf(s[5], s[13]);               \
        float a6 = fmaxf(s[6], s[14]), a7 = fmaxf(s[7], s[15]);               \
        a0 = fmaxf(a0, a4); a1 = fmaxf(a1, a5);                               \
        a2 = fmaxf(a2, a6); a3 = fmaxf(a3, a7);                               \
        float smax = fmaxf(fmaxf(a0, a1), fmaxf(a2, a3));                     \
        const int resc_i = __any(smax > m_run + 8.0f);                        \
        char* Fw = lds + FOFF + ((jq * 2 + kb_) * 2 + rg) * 160;              \
        if (resc_i) {                                                         \
            float sm2 = fmaxf(smax, __shfl_xor(smax, 32));                    \
            float mnew = fmaxf(m_run, sm2);                                   \
            float corr = exp2a(m_run - mnew);                                 \
            m_run = mnew; l_run *= corr;                                      \
            if (lane < 32) *reinterpret_cast<float*>(Fw + 16 + l31 * 4) = corr; \
        }                                                                     \
        if (lane == 0) *reinterpret_cast<int*>(Fw) = resc_i;                  \
        float p_[16]; float lsum = 0.f;                                       \
        _Pragma("unroll")                                                     \
        for (int r = 0; r < 16; ++r) { p_[r] = exp2a(s[r] - m_run); lsum += p_[r]; } \
        l_run += lsum;                                                        \
        unsigned int X0 = cvtpk(p_[0],  p_[1]),  X1 = cvtpk(p_[2],  p_[3]);   \
        unsigned int Y0 = cvtpk(p_[4],  p_[5]),  Y1 = cvtpk(p_[6],  p_[7]);   \
        unsigned int W0 = cvtpk(p_[8],  p_[9]),  W1 = cvtpk(p_[10], p_[11]);  \
        unsigned int V0 = cvtpk(p_[12], p_[13]), V1 = cvtpk(p_[14], p_[15]);  \
        pl32swap(X0, Y0); pl32swap(X1, Y1);                                   \
        pl32swap(W0, V0); pl32swap(W1, V1);                                   \
        char* Pw = lds + POFF + ((jq * 2 + kb_) * 2 + rg) * 2048;             \
        *reinterpret_cast<u32x4*>(Pw + lane * 16) = u32x4{X0, X1, Y0, Y1};    \
        *reinterpret_cast<u32x4*>(Pw + 1024 + lane * 16) = u32x4{W0, W1, V0, V1}; \
    } while (0)

    // ---- consumer step: PV for tile TP (P/F[TP&1], V[TP%3]) ----
#define CONS_STEP(TP) do {                                                    \
        const int pb_ = (TP) & 1;                                             \
        const int vs_ = (TP) % 3;                                             \
        const char* Pr0 = lds + POFF + ((jq * 2 + pb_) * 2 + 0) * 2048;       \
        const char* Pr1 = lds + POFF + ((jq * 2 + pb_) * 2 + 1) * 2048;       \
        short8 p00 = *reinterpret_cast<const short8*>(Pr0 + lane * 16);       \
        short8 p01 = *reinterpret_cast<const short8*>(Pr0 + 1024 + lane * 16);\
        short8 p10 = *reinterpret_cast<const short8*>(Pr1 + lane * 16);       \
        short8 p11 = *reinterpret_cast<const short8*>(Pr1 + 1024 + lane * 16);\
        const char* F0 = lds + FOFF + ((jq * 2 + pb_) * 2 + 0) * 160;         \
        const char* F1 = lds + FOFF + ((jq * 2 + pb_) * 2 + 1) * 160;         \
        const int f0 = *reinterpret_cast<const int*>(F0);                     \
        const int f1 = *reinterpret_cast<const int*>(F1);                     \
        if (f0) { float c0 = *reinterpret_cast<const float*>(F0 + 16 + l31 * 4); \
            _Pragma("unroll")                                                 \
            for (int g = 0; g < 4; ++g)                                       \
                _Pragma("unroll")                                             \
                for (int r = 0; r < 16; ++r) acc[0][g][r] *= c0; }            \
        if (f1) { float c1 = *reinterpret_cast<const float*>(F1 + 16 + l31 * 4); \
            _Pragma("unroll")                                                 \
            for (int g = 0; g < 4; ++g)                                       \
                _Pragma("unroll")                                             \
                for (int r = 0; r < 16; ++r) acc[1][g][r] *= c1; }            \
        const char* vb_ = ldsV + vs_ * 16384;                                 \
        __builtin_amdgcn_s_setprio(1);                                        \
        _Pragma("unroll")                                                     \
        for (int gl = 0; gl < 4; ++gl) {                                      \
            const char* vrow = vb_ + (ch * 4 + gl) * 2048;                    \
            short8 va0 = *reinterpret_cast<const short8*>(vrow + lane * 16);  \
            short8 va1 = *reinterpret_cast<const short8*>(vrow + 1024 + lane * 16); \
            acc[0][gl] = __builtin_amdgcn_mfma_f32_32x32x16_bf16(va0, p00, acc[0][gl], 0, 0, 0); \
            acc[0][gl] = __builtin_amdgcn_mfma_f32_32x32x16_bf16(va1, p01, acc[0][gl], 0, 0, 0); \
            acc[1][gl] = __builtin_amdgcn_mfma_f32_32x32x16_bf16(va0, p10, acc[1][gl], 0, 0, 0); \
            acc[1][gl] = __builtin_amdgcn_mfma_f32_32x32x16_bf16(va1, p11, acc[1][gl], 0, 0, 0); \
        }                                                                     \
        __builtin_amdgcn_s_setprio(0);                                        \
    } while (0)

#define STAGE_K(T) do {                                                       \
        const char* ks = (const char*)(ktb + (size_t)(jt0 + (T)) * 1024);     \
        gload16(ks + rg * 1024 + lane * 16,                                   \
                ldsK + ((T) & 1) * 2048 + rg * 1024);                         \
    } while (0)

#define STAGE_V(T) do {                                                       \
        const char* vs = (const char*)(vtb + (size_t)(jt0 + (T)) * 8192);     \
        char* vw = ldsV + ((T) % 3) * 16384;                                  \
        _Pragma("unroll")                                                     \
        for (int s2 = 0; s2 < 8; ++s2)                                        \
            gload16(vs + (ch * 8 + s2) * 1024 + lane * 16,                    \
                    vw + (ch * 8 + s2) * 1024);                               \
    } while (0)

    // ---- prologue: stage tile 0; then warm step (P[0] + stage tile 1) ----
    if (prod) STAGE_K(0); else STAGE_V(0);
    __syncthreads();
    if (prod) { STAGE_K(1); PROD_STEP(0); } else { STAGE_V(1); }
    __syncthreads();

    // ---- main loop: producer on tile t, consumer on tile t-1 ----
    #pragma unroll 1
    for (int t = 1; t < 64; ++t) {
        if (prod) {
            if (t < 63) STAGE_K(t + 1);
            PROD_STEP(t);
        } else {
            if (t < 63) STAGE_V(t + 1);
            CONS_STEP(t - 1);
        }
        __syncthreads();
    }
    // consumer finishes tile 63
    if (!prod) CONS_STEP(63);
    __syncthreads();

#undef PROD_STEP
#undef CONS_STEP
#undef STAGE_K
#undef STAGE_V

    // ---- m/l publish (producers) ----
    if (prod && lane < 32) {
        float l_tot = l_run + __shfl_xor(l_run, 32);
        *reinterpret_cast<float*>(lds + MOFF + wave * 128 + l31 * 4) = m_run;
        *reinterpret_cast<float*>(lds + MOFF + 512 + wave * 128 + l31 * 4) = l_tot;
    }
    __syncthreads();

#define MSH(pw) (*reinterpret_cast<const float*>(lds + MOFF + (pw) * 128 + l31 * 4))
#define LSH(pw) (*reinterpret_cast<const float*>(lds + MOFF + 512 + (pw) * 128 + l31 * 4))

    // ---- consumers: weight by exp2(m_jq - M) per row-group ----
    if (!prod) {
        #pragma unroll
        for (int rgg = 0; rgg < 2; ++rgg) {
            const float m0 = MSH(rgg * 2 + 0), m1 = MSH(rgg * 2 + 1);
            const float M = fmaxf(m0, m1);
            const float wgt = exp2a(MSH(rgg * 2 + jq) - M);
            #pragma unroll
            for (int g = 0; g < 4; ++g)
                #pragma unroll
                for (int r = 0; r < 16; ++r) acc[rgg][g][r] *= wgt;
        }
    }
    // jq1 consumers dump; jq0 consumers merge + write back; all waves store
    if (!prod && jq == 1) {
        #pragma unroll
        for (int rgg = 0; rgg < 2; ++rgg)
            #pragma unroll
            for (int gl = 0; gl < 4; ++gl)
                #pragma unroll
                for (int r4 = 0; r4 < 4; ++r4) {
                    f32x4 tv;
                    #pragma unroll
                    for (int e = 0; e < 4; ++e) tv[e] = acc[rgg][gl][4 * r4 + e];
                    *reinterpret_cast<f32x4*>(lds +
                        ((((ch * 2 + rgg) * 4 + gl) * 4 + r4) * 64 + lane) * 16) = tv;
                }
    }
    __syncthreads();
    if (!prod && jq == 0) {
        #pragma unroll
        for (int rgg = 0; rgg < 2; ++rgg)
            #pragma unroll
            for (int gl = 0; gl < 4; ++gl)
                #pragma unroll
                for (int r4 = 0; r4 < 4; ++r4) {
                    f32x4* pD = reinterpret_cast<f32x4*>(lds +
                        ((((ch * 2 + rgg) * 4 + gl) * 4 + r4) * 64 + lane) * 16);
                    f32x4 tv = *pD;
                    #pragma unroll
                    for (int e = 0; e < 4; ++e) tv[e] += acc[rgg][gl][4 * r4 + e];
                    *pD = tv;
                }
    }
    __syncthreads();

    // ---- store: 8 waves x 2 (ch,rg,gl) combos each ----
    const float gma = gamma[0];
    #pragma unroll
    for (int k = 0; k < 2; ++k) {
        const int idx = wave * 2 + k;        // 0..15
        const int chh = idx >> 3, rgg = (idx >> 2) & 1, gl = idx & 3;
        const int g = chh * 4 + gl;
        const float m0 = MSH(rgg * 2 + 0), m1 = MSH(rgg * 2 + 1);
        const float M = fmaxf(m0, m1);
        const float L = exp2a(m0 - M) * LSH(rgg * 2 + 0)
                      + exp2a(m1 - M) * LSH(rgg * 2 + 1);
        const float invL = 1.f / L;
        const int i = i0 + rgg * 32 + l31;
        #pragma unroll
        for (int r4 = 0; r4 < 4; ++r4) {
            f32x4 v = *reinterpret_cast<const f32x4*>(lds +
                ((((chh * 2 + rgg) * 4 + gl) * 4 + r4) * 64 + lane) * 16);
            #pragma unroll
            for (int e = 0; e < 4; ++e) {
                const int c = 32 * g + e + 8 * r4 + 4 * h2;
                const size_t off = ((size_t)b * C_ + c) * N_ + i;
                out[off] = gma * v[e] * invL + x[off];
            }
        }
    }
#undef MSH
#undef LSH
}

extern "C" void kernel_launch(void* const* d_in, const int* in_sizes, int n_in,
                              void* d_out, int out_size, void* d_ws, size_t ws_size,
                              hipStream_t stream) {
    const float* x     = (const float*)d_in[0];
    const float* Wq    = (const float*)d_in[1];
    const float* bq    = (const float*)d_in[2];
    const float* Wk    = (const float*)d_in[3];
    const float* bk    = (const float*)d_in[4];
    const float* Wv    = (const float*)d_in[5];
    const float* bv    = (const float*)d_in[6];
    const float* gamma = (const float*)d_in[7];
    float* out = (float*)d_out;

    unsigned short* ws = (unsigned short*)d_ws;
    unsigned short* qb    = ws;                                 // B*N*32 bf16
    unsigned short* kfrag = qb + (size_t)B_ * N_ * INTER_;      // B*128*1024 bf16
    unsigned short* vfrag = kfrag + (size_t)B_ * 128 * 1024;    // B*128*8192 bf16
    unsigned short* wb    = vfrag + (size_t)B_ * 128 * 8192;    // 320*256 bf16

    prep_kernel<<<dim3(320), 256, 0, stream>>>(Wq, Wk, Wv, wb);
    qkv_kernel<<<dim3(B_ * (N_ / 64)), 256, 0, stream>>>(
        x, wb, bq, bk, bv, qb, kfrag, vfrag);
    attn_kernel<<<dim3(256), 512, 0, stream>>>(
        qb, kfrag, vfrag, x, gamma, out);
}

// Round 14
// 81.581 us; speedup vs baseline: 1.1653x; 1.1653x over previous
//
#include <hip/hip_runtime.h>

#define B_ 4
#define C_ 256
#define N_ 4096
#define INTER_ 32

typedef __attribute__((ext_vector_type(8))) short short8;
typedef __attribute__((ext_vector_type(4))) float f32x4;
typedef __attribute__((ext_vector_type(16))) float f32x16;
typedef __attribute__((ext_vector_type(4))) unsigned int u32x4;

#define TILEB 16384              // staged bytes per j-tile: V only (K in regs)
#define NSTG  (8 * TILEB)        // 4 jq * 2 buf = 131072 B

static __device__ __forceinline__ unsigned short f2bf(float f) {
    unsigned int u = __builtin_bit_cast(unsigned int, f);
    u += 0x7fff + ((u >> 16) & 1);   // round-to-nearest-even
    return (unsigned short)(u >> 16);
}

static __device__ __forceinline__ unsigned int cvtpk(float lo, float hi) {
    unsigned int r;
    asm("v_cvt_pk_bf16_f32 %0, %1, %2" : "=v"(r) : "v"(lo), "v"(hi));
    return r;
}

static __device__ __forceinline__ void pl32swap(unsigned int& a, unsigned int& b) {
    asm("v_permlane32_swap_b32 %0, %1" : "+v"(a), "+v"(b));
}

static __device__ __forceinline__ float exp2a(float x) {   // bare v_exp_f32: 2^x
    float r;
    asm("v_exp_f32 %0, %1" : "=v"(r) : "v"(x));
    return r;
}

static __device__ __forceinline__ void gload16(const void* g, void* l) {
    __builtin_amdgcn_global_load_lds(
        (const __attribute__((address_space(1))) void*)g,
        (__attribute__((address_space(3))) void*)l, 16, 0, 0);
}

// ---------------- W prep: concat + bf16 convert ----------------
__global__ __launch_bounds__(256) void prep_kernel(
    const float* __restrict__ Wq, const float* __restrict__ Wk,
    const float* __restrict__ Wv, unsigned short* __restrict__ wb)
{
    int i = blockIdx.x * 256 + threadIdx.x;      // 0 .. 320*256-1
    int row = i >> 8, col = i & 255;
    float v;
    if (row < 32)      v = Wq[row * 256 + col];
    else if (row < 64) v = Wk[(row - 32) * 256 + col];
    else               v = Wv[(row - 64) * 256 + col];
    wb[i] = f2bf(v);
}

// ---------------- QKV projection as MFMA GEMM ----------------
// q: [b][n][32] bf16, pre-scaled by log2(e)/sqrt(32) (exp2-domain softmax).
// K/V emitted in MFMA-fragment-linear tiles (see round 6).
__global__ __launch_bounds__(256) void qkv_kernel(
    const float* __restrict__ x, const unsigned short* __restrict__ wb,
    const float* __restrict__ bq, const float* __restrict__ bk,
    const float* __restrict__ bv,
    unsigned short* __restrict__ qb, unsigned short* __restrict__ kfrag,
    unsigned short* __restrict__ vfrag)
{
    const int tid  = threadIdx.x;
    const int wave = tid >> 6;
    const int lane = tid & 63;
    const int l31  = lane & 31;
    const int h2   = lane >> 5;
    const int b    = blockIdx.x >> 6;
    const int n0   = (blockIdx.x & 63) * 64;

    __shared__ unsigned int xsh[64 * 129];   // [n][c/2] u32, row stride 129 dwords

    {
        const float* xb = x + ((size_t)b * C_ + 64 * wave) * N_ + n0 + lane;
        unsigned int* dst = xsh + (size_t)lane * 129 + 32 * wave;
        #pragma unroll 8
        for (int s = 0; s < 32; ++s) {
            float v0 = xb[(size_t)(2 * s) * N_];
            float v1 = xb[(size_t)(2 * s + 1) * N_];
            dst[s] = (unsigned int)f2bf(v0) | ((unsigned int)f2bf(v1) << 16);
        }
    }
    __syncthreads();

    const float rs = 0.25504183f;   // log2(e)/sqrt(32) folded into q

    #pragma unroll
    for (int u = 0; u < 5; ++u) {
        const int unit = wave + 4 * u;       // 0..19
        const int ch = unit >> 1;            // 0..9
        const int ns = unit & 1;
        const int ncol = n0 + 32 * ns + l31;
        const int jt = (n0 >> 5) + ns;

        const float* bias = (ch == 0) ? bq : (ch == 1) ? bk : (bv + (ch - 2) * 32);
        f32x16 acc;
        #pragma unroll
        for (int r = 0; r < 16; ++r)
            acc[r] = bias[(r & 3) + 8 * (r >> 2) + 4 * h2];

        const unsigned short* wrow = wb + ((size_t)(ch * 32 + l31)) * 256 + 8 * h2;
        const unsigned int*   xrow = xsh + (size_t)(32 * ns + l31) * 129 + 4 * h2;

        #pragma unroll
        for (int kk = 0; kk < 16; ++kk) {
            short8 wa = *reinterpret_cast<const short8*>(wrow + 16 * kk);
            short8 xf = *reinterpret_cast<const short8*>(xrow + 8 * kk);
            acc = __builtin_amdgcn_mfma_f32_32x32x16_bf16(wa, xf, acc, 0, 0, 0);
        }

        if (ch == 0) {
            unsigned short* dst = qb + ((size_t)b * N_ + ncol) * 32;
            #pragma unroll
            for (int q = 0; q < 4; ++q) {
                unsigned int w0 = (unsigned int)f2bf(acc[4 * q] * rs)
                                | ((unsigned int)f2bf(acc[4 * q + 1] * rs) << 16);
                unsigned int w1 = (unsigned int)f2bf(acc[4 * q + 2] * rs)
                                | ((unsigned int)f2bf(acc[4 * q + 3] * rs) << 16);
                unsigned int* p = reinterpret_cast<unsigned int*>(dst + 4 * h2 + 8 * q);
                p[0] = w0; p[1] = w1;
            }
        } else if (ch == 1) {
            // K fragment tile: acc[r] = K[kdim=co][j_local=l31]
            unsigned short* kt = kfrag + ((size_t)b * 128 + jt) * 1024;
            #pragma unroll
            for (int r = 0; r < 16; ++r) {
                const int co = (r & 3) + 8 * (r >> 2) + 4 * h2;
                const int addr = ((co >> 4) << 9) + ((l31 + 32 * ((co >> 3) & 1)) << 3)
                               + (co & 7);
                kt[addr] = f2bf(acc[r]);
            }
        } else {
            // V fragment tile: acc[r] = V[c=32g+co][j_local=l31]
            const int g = ch - 2;
            unsigned short* vt_ = vfrag + (((size_t)b * 128 + jt) * 8 + g) * 1024;
            #pragma unroll
            for (int r = 0; r < 16; ++r) {
                const int co = (r & 3) + 8 * (r >> 2) + 4 * h2;
                const int addr = ((l31 >> 4) << 9) + ((co + 32 * ((l31 >> 3) & 1)) << 3)
                               + (l31 & 7);
                vt_[addr] = f2bf(acc[r]);
            }
        }
    }
}

// ---------------- Flash attention (r10 structure, K-in-regs, V-only LDS) ---
// Flat grid 256, XCD-batch-affinity bijective decode. block 512 = 8 waves =
// 4 j-quarters x 2 q-subwaves. Per 32-key step: prefetch next K fragments
// straight into REGISTERS (2 coalesced 1KB global loads, issued BEFORE the V
// staging so their wait leaves the V pipeline in flight), stage next V tile
// via 16 global_load_lds (8 per qs wave, no branching), lane-linear
// conflict-free ds_read_b128 for V, swapped-operand MFMA flash with
// exp2-domain lane-local softmax (bare v_exp_f32), 4-way phased j-combine.
__global__ __launch_bounds__(512) void attn_kernel(
    const unsigned short* __restrict__ qb, const unsigned short* __restrict__ kfrag,
    const unsigned short* __restrict__ vfrag,
    const float* __restrict__ x, const float* __restrict__ gamma,
    float* __restrict__ out)
{
    const int tid  = threadIdx.x;
    const int wave = tid >> 6;
    const int lane = tid & 63;
    const int l31  = lane & 31;
    const int h2   = lane >> 5;
    const int jq   = wave >> 1;
    const int qs   = wave & 1;

    // XCD-affinity decode (bijective): bid = slot*8 + xcd
    const int bid  = blockIdx.x;
    const int xcd  = bid & 7;
    const int slot = bid >> 3;
    const int b    = xcd >> 1;               // 2 XCDs per batch
    const int ib   = slot * 2 + (xcd & 1);   // i-tile 0..63
    const int iq   = ib * 64 + 32 * qs;

    __shared__ char lds[NSTG];
    __shared__ float m_sh[8][32];
    __shared__ float l_sh[8][32];

    const unsigned short* vtb = vfrag + (size_t)b * 128 * 8192;
    const unsigned short* ktb = kfrag + (size_t)b * 128 * 1024;

    char* reg0 = lds + (jq * 2) * TILEB;
    char* reg1 = reg0 + TILEB;

    // Q B-fragments (one-time scattered load)
    short8 qf0 = *reinterpret_cast<const short8*>(
        qb + ((size_t)b * N_ + iq + l31) * 32 + 8 * h2);
    short8 qf1 = *reinterpret_cast<const short8*>(
        qb + ((size_t)b * N_ + iq + l31) * 32 + 8 * h2 + 16);

    f32x16 acc[8];
    #pragma unroll
    for (int g = 0; g < 8; ++g)
        #pragma unroll
        for (int r = 0; r < 16; ++r) acc[g][r] = 0.f;

    float m_run = 0.f;   // defer-max init (exp2 domain)
    float l_run = 0.f;
    const f32x16 z16 = {};

    // strength-reduced staging pointers for this jq/qs
    const char* vstep = (const char*)vtb + (size_t)(jq * 32) * 16384
                      + qs * 8192 + lane * 16;
    const char* kptr  = (const char*)ktb + (size_t)(jq * 32) * 2048 + lane * 16;

    // ---- prologue: stage V tile 0; load K_0 fragments into regs ----
    #pragma unroll
    for (int s2 = 0; s2 < 8; ++s2)
        gload16(vstep + s2 * 1024, reg0 + qs * 8192 + s2 * 1024);
    short8 kc0 = *reinterpret_cast<const short8*>(kptr);
    short8 kc1 = *reinterpret_cast<const short8*>(kptr + 1024);
    kptr += 2048;
    __syncthreads();

    #pragma unroll 1
    for (int t = 0; t < 32; ++t) {
        char* cur = (t & 1) ? reg1 : reg0;
        char* nxt = (t & 1) ? reg0 : reg1;

        // ---- prefetch K_{t+1} into regs FIRST, then stage V_{t+1} ----
        short8 kn0, kn1;
        if (t < 31) {
            kn0 = *reinterpret_cast<const short8*>(kptr);
            kn1 = *reinterpret_cast<const short8*>(kptr + 1024);
            kptr += 2048;
            vstep += 16384;
            #pragma unroll
            for (int s2 = 0; s2 < 8; ++s2)
                gload16(vstep + s2 * 1024, nxt + qs * 8192 + s2 * 1024);
        }

        // ---- QK^T (swapped): S^T[j][i] from register K fragments ----
        f32x16 s = __builtin_amdgcn_mfma_f32_32x32x16_bf16(kc0, qf0, z16, 0, 0, 0);
        s = __builtin_amdgcn_mfma_f32_32x32x16_bf16(kc1, qf1, s, 0, 0, 0);

        // ---- online softmax (exp2 domain), lane-local (i = l31) ----
        float a0 = fmaxf(s[0], s[8]),  a1 = fmaxf(s[1], s[9]);
        float a2 = fmaxf(s[2], s[10]), a3 = fmaxf(s[3], s[11]);
        float a4 = fmaxf(s[4], s[12]), a5 = fmaxf(s[5], s[13]);
        float a6 = fmaxf(s[6], s[14]), a7 = fmaxf(s[7], s[15]);
        a0 = fmaxf(a0, a4); a1 = fmaxf(a1, a5); a2 = fmaxf(a2, a6); a3 = fmaxf(a3, a7);
        float smax = fmaxf(fmaxf(a0, a1), fmaxf(a2, a3));

        if (__any(smax > m_run + 8.0f)) {    // defer-max: rare slow path
            float sm2 = fmaxf(smax, __shfl_xor(smax, 32));
            float mnew = fmaxf(m_run, sm2);
            float corr = exp2a(m_run - mnew);
            m_run = mnew;
            l_run *= corr;
            #pragma unroll
            for (int g = 0; g < 8; ++g)
                #pragma unroll
                for (int r = 0; r < 16; ++r) acc[g][r] *= corr;
        }

        float p[16];
        float lsum = 0.f;
        #pragma unroll
        for (int r = 0; r < 16; ++r) { p[r] = exp2a(s[r] - m_run); lsum += p[r]; }
        l_run += lsum;

        unsigned int X0 = cvtpk(p[0],  p[1]),  X1 = cvtpk(p[2],  p[3]);
        unsigned int Y0 = cvtpk(p[4],  p[5]),  Y1 = cvtpk(p[6],  p[7]);
        unsigned int W0 = cvtpk(p[8],  p[9]),  W1 = cvtpk(p[10], p[11]);
        unsigned int V0 = cvtpk(p[12], p[13]), V1 = cvtpk(p[14], p[15]);
        pl32swap(X0, Y0); pl32swap(X1, Y1);
        pl32swap(W0, V0); pl32swap(W1, V1);
        short8 pb0 = __builtin_bit_cast(short8, u32x4{X0, X1, Y0, Y1});
        short8 pb1 = __builtin_bit_cast(short8, u32x4{W0, W1, V0, V1});

        // ---- PV: lane-linear V fragment reads from LDS ----
        __builtin_amdgcn_s_setprio(1);
        #pragma unroll
        for (int g = 0; g < 8; ++g) {
            short8 va0 = *reinterpret_cast<const short8*>(cur + g * 2048 + lane * 16);
            short8 va1 = *reinterpret_cast<const short8*>(cur + g * 2048 + 1024 + lane * 16);
            acc[g] = __builtin_amdgcn_mfma_f32_32x32x16_bf16(va0, pb0, acc[g], 0, 0, 0);
            acc[g] = __builtin_amdgcn_mfma_f32_32x32x16_bf16(va1, pb1, acc[g], 0, 0, 0);
        }
        __builtin_amdgcn_s_setprio(0);

        if (t < 31) { kc0 = kn0; kc1 = kn1; }   // rotate K regs

        __syncthreads();   // drains vmcnt (next V tile landed) + guards buffers
    }

    // ---- 4-way j-combine ----
    float l_tot = l_run + __shfl_xor(l_run, 32);
    if (lane < 32) { m_sh[wave][lane] = m_run; l_sh[wave][lane] = l_tot; }
    __syncthreads();

    float M = -1e30f, L = 0.f;
    #pragma unroll
    for (int w2 = 0; w2 < 4; ++w2) M = fmaxf(M, m_sh[w2 * 2 + qs][l31]);
    #pragma unroll
    for (int w2 = 0; w2 < 4; ++w2)
        L += exp2a(m_sh[w2 * 2 + qs][l31] - M) * l_sh[w2 * 2 + qs][l31];
    const float wgt = exp2a(m_run - M);
    #pragma unroll
    for (int g = 0; g < 8; ++g)
        #pragma unroll
        for (int r = 0; r < 16; ++r) acc[g][r] *= wgt;

    // phase A: jq2,jq3 dump -> D[(jq-2)*2+qs]; jq0,jq1 add
    if (jq >= 2) {
        f32x4* Dr = (f32x4*)(lds + ((jq - 2) * 2 + qs) * 32768);
        #pragma unroll
        for (int g = 0; g < 8; ++g)
            #pragma unroll
            for (int r4 = 0; r4 < 4; ++r4) {
                f32x4 tv;
                #pragma unroll
                for (int e = 0; e < 4; ++e) tv[e] = acc[g][4 * r4 + e];
                Dr[(g * 4 + r4) * 64 + lane] = tv;
            }
    }
    __syncthreads();
    if (jq < 2) {
        const f32x4* Dr = (const f32x4*)(lds + (jq * 2 + qs) * 32768);
        #pragma unroll
        for (int g = 0; g < 8; ++g)
            #pragma unroll
            for (int r4 = 0; r4 < 4; ++r4) {
                f32x4 tv = Dr[(g * 4 + r4) * 64 + lane];
                #pragma unroll
                for (int e = 0; e < 4; ++e) acc[g][4 * r4 + e] += tv[e];
            }
    }
    __syncthreads();
    // phase B: jq1 dump -> D[2+qs]; jq0 add; jq0 dump final -> D[qs]
    if (jq == 1) {
        f32x4* Dr = (f32x4*)(lds + (2 + qs) * 32768);
        #pragma unroll
        for (int g = 0; g < 8; ++g)
            #pragma unroll
            for (int r4 = 0; r4 < 4; ++r4) {
                f32x4 tv;
                #pragma unroll
                for (int e = 0; e < 4; ++e) tv[e] = acc[g][4 * r4 + e];
                Dr[(g * 4 + r4) * 64 + lane] = tv;
            }
    }
    __syncthreads();
    if (jq == 0) {
        const f32x4* Dr = (const f32x4*)(lds + (2 + qs) * 32768);
        f32x4* Dw = (f32x4*)(lds + qs * 32768);
        #pragma unroll
        for (int g = 0; g < 8; ++g)
            #pragma unroll
            for (int r4 = 0; r4 < 4; ++r4) {
                f32x4 tv = Dr[(g * 4 + r4) * 64 + lane];
                #pragma unroll
                for (int e = 0; e < 4; ++e) tv[e] += acc[g][4 * r4 + e];
                Dw[(g * 4 + r4) * 64 + lane] = tv;
            }
    }
    __syncthreads();

    // ---- store: wave w -> q-subwave (w&1)==qs, g-pair (w>>1)==jq ----
    const float gma  = gamma[0];
    const float invL = 1.f / L;
    const f32x4* Ds = (const f32x4*)(lds + qs * 32768);
    const int i = iq + l31;
    #pragma unroll
    for (int gi = 0; gi < 2; ++gi) {
        const int g = jq * 2 + gi;
        #pragma unroll
        for (int r4 = 0; r4 < 4; ++r4) {
            f32x4 v = Ds[(g * 4 + r4) * 64 + lane];
            #pragma unroll
            for (int e = 0; e < 4; ++e) {
                const int c = 32 * g + e + 8 * r4 + 4 * h2;
                const size_t off = ((size_t)b * C_ + c) * N_ + i;
                out[off] = gma * v[e] * invL + x[off];
            }
        }
    }
}

extern "C" void kernel_launch(void* const* d_in, const int* in_sizes, int n_in,
                              void* d_out, int out_size, void* d_ws, size_t ws_size,
                              hipStream_t stream) {
    const float* x     = (const float*)d_in[0];
    const float* Wq    = (const float*)d_in[1];
    const float* bq    = (const float*)d_in[2];
    const float* Wk    = (const float*)d_in[3];
    const float* bk    = (const float*)d_in[4];
    const float* Wv    = (const float*)d_in[5];
    const float* bv    = (const float*)d_in[6];
    const float* gamma = (const float*)d_in[7];
    float* out = (float*)d_out;

    unsigned short* ws = (unsigned short*)d_ws;
    unsigned short* qb    = ws;                                 // B*N*32 bf16
    unsigned short* kfrag = qb + (size_t)B_ * N_ * INTER_;      // B*128*1024 bf16
    unsigned short* vfrag = kfrag + (size_t)B_ * 128 * 1024;    // B*128*8192 bf16
    unsigned short* wb    = vfrag + (size_t)B_ * 128 * 8192;    // 320*256 bf16

    prep_kernel<<<dim3(320), 256, 0, stream>>>(Wq, Wk, Wv, wb);
    qkv_kernel<<<dim3(B_ * (N_ / 64)), 256, 0, stream>>>(
        x, wb, bq, bk, bv, qb, kfrag, vfrag);
    attn_kernel<<<dim3(256), 512, 0, stream>>>(
        qb, kfrag, vfrag, x, gamma, out);
}